// Round 5
// baseline (491.740 us; speedup 1.0000x reference)
//
#include <hip/hip_runtime.h>
#include <hip/hip_bf16.h>
#include <stdint.h>

#define B_SZ 4
#define L_SEQ 2048
#define EMB 2048
#define NH 16
#define HD 128
#define BLROWS (B_SZ * L_SEQ)   // 8192

typedef __bf16 bf16;
typedef __bf16 bf16x8 __attribute__((ext_vector_type(8)));
typedef __bf16 bf16x4 __attribute__((ext_vector_type(4)));
typedef float f32x4 __attribute__((ext_vector_type(4)));

#define MFMA16(A, Bv, C) __builtin_amdgcn_mfma_f32_16x16x32_bf16(A, Bv, C, 0, 0, 0)

__device__ __forceinline__ void gll16(bf16* l, const bf16* g) {
  __builtin_amdgcn_global_load_lds(
      (const __attribute__((address_space(1))) unsigned int*)g,
      (__attribute__((address_space(3))) unsigned int*)l, 16, 0, 0);
}

// ---------------- fp32 -> bf16 convert ----------------
__global__ __launch_bounds__(256) void f2b_kernel(const float* __restrict__ in,
                                                  bf16* __restrict__ out, int n4) {
  int i = blockIdx.x * blockDim.x + threadIdx.x;
  int stride = gridDim.x * blockDim.x;
  for (; i < n4; i += stride) {
    float4 v = ((const float4*)in)[i];
    bf16x4 o = {(bf16)v.x, (bf16)v.y, (bf16)v.z, (bf16)v.w};
    ((bf16x4*)out)[i] = o;
  }
}

// ------- 256x256 GEMM, BK=64, 2-buffer, 4-phase barrier-pair schedule -------
// C[M][N] = A[M][K]*B[N][K]^T. 8 waves (2Mx4N), wave output 128x64.
// Per K-tile: phase mp computes m-quadrant {2mp,2mp+1} x n0..3 x ks0..1 (16 MFMA).
// B-frags (8) loaded once at phase 0, held in regs. All 8 staging glls for
// tile t+1 issued at phase 0 -> boundary vmcnt(0) has ~3 phases of cover.
// LDS rows 128B, chunk swizzle c ^ (row&7); gll source pre-swizzled (m173).
template <int EPI>
__global__ __launch_bounds__(512, 2) void gemm256(const bf16* __restrict__ A,
                                                  const bf16* __restrict__ Bm,
                                                  bf16* __restrict__ Cq,
                                                  bf16* __restrict__ Ck,
                                                  bf16* __restrict__ Cvt,
                                                  float* __restrict__ Cf,
                                                  int K) {
  __shared__ bf16 Abuf[2][256 * 64];   // 32 KB each
  __shared__ bf16 Bbuf[2][256 * 64];
  const int tid = threadIdx.x, lane = tid & 63, w = tid >> 6;
  const int wr = w >> 2, wc = w & 3;
  const int l15 = lane & 15;

  const int q8 = gridDim.x >> 3;
  const int wg = ((int)blockIdx.x & 7) * q8 + ((int)blockIdx.x >> 3);
  const int bm = (wg & 31) * 256;
  const int bn = (wg >> 5) * 256;
  const int NT = K >> 6;

  // staging: 4 glls each for A and B; g: id=g*512+tid; row=id>>3; chunk=id&7
  size_t sAg[4], sBg[4];
  int sdst[4];
#pragma unroll
  for (int g = 0; g < 4; g++) {
    int id = g * 512 + tid;
    int row = id >> 3, c = id & 7;
    int scol = ((c ^ (row & 7)) * 8);
    sAg[g] = (size_t)(bm + row) * K + scol;
    sBg[g] = (size_t)(bn + row) * K + scol;
    sdst[g] = id * 8;
  }

  // fragment read offsets (swizzled): row*64 + ((cl ^ (row&7))*8), cl=ks*4+(lane>>4)
  int aoff[8][2], boff[4][2];
#pragma unroll
  for (int m = 0; m < 8; m++)
#pragma unroll
    for (int ks = 0; ks < 2; ks++) {
      int row = wr * 128 + m * 16 + l15;
      int cl = ks * 4 + (lane >> 4);
      aoff[m][ks] = row * 64 + ((cl ^ (row & 7)) * 8);
    }
#pragma unroll
  for (int n = 0; n < 4; n++)
#pragma unroll
    for (int ks = 0; ks < 2; ks++) {
      int row = wc * 64 + n * 16 + l15;
      int cl = ks * 4 + (lane >> 4);
      boff[n][ks] = row * 64 + ((cl ^ (row & 7)) * 8);
    }

  f32x4 acc[8][4] = {};

  // prologue: stage tile 0
#pragma unroll
  for (int g = 0; g < 4; g++) {
    gll16(&Abuf[0][sdst[g]], A + sAg[g]);
    gll16(&Bbuf[0][sdst[g]], Bm + sBg[g]);
  }
  asm volatile("s_waitcnt vmcnt(0)" ::: "memory");
  __builtin_amdgcn_s_barrier();
  asm volatile("" ::: "memory");

  for (int t = 0; t < NT; ++t) {
    const bf16* __restrict__ Ab = Abuf[t & 1];
    const bf16* __restrict__ Bb = Bbuf[t & 1];
    bf16* __restrict__ An = Abuf[(t + 1) & 1];
    bf16* __restrict__ Bn = Bbuf[(t + 1) & 1];
    const size_t k1 = (size_t)(t + 1) << 6;
    const bool pre = (t + 1 < NT);

    bf16x8 bq[4][2];

#pragma unroll
    for (int mp = 0; mp < 4; mp++) {
      // ds reads for this phase
      bf16x8 a0k0 = *(const bf16x8*)&Ab[aoff[2 * mp][0]];
      bf16x8 a0k1 = *(const bf16x8*)&Ab[aoff[2 * mp][1]];
      bf16x8 a1k0 = *(const bf16x8*)&Ab[aoff[2 * mp + 1][0]];
      bf16x8 a1k1 = *(const bf16x8*)&Ab[aoff[2 * mp + 1][1]];
      if (mp == 0) {
#pragma unroll
        for (int n = 0; n < 4; n++) {
          bq[n][0] = *(const bf16x8*)&Bb[boff[n][0]];
          bq[n][1] = *(const bf16x8*)&Bb[boff[n][1]];
        }
        if (pre) {
#pragma unroll
          for (int g = 0; g < 4; g++) {
            gll16(&An[sdst[g]], A + sAg[g] + k1);
            gll16(&Bn[sdst[g]], Bm + sBg[g] + k1);
          }
        }
      }
      __builtin_amdgcn_s_barrier();                       // open
      asm volatile("s_waitcnt lgkmcnt(0)" ::: "memory");
      __builtin_amdgcn_sched_barrier(0);
      __builtin_amdgcn_s_setprio(1);
#pragma unroll
      for (int n = 0; n < 4; n++) {
        acc[2 * mp][n] = MFMA16(a0k0, bq[n][0], acc[2 * mp][n]);
        acc[2 * mp][n] = MFMA16(a0k1, bq[n][1], acc[2 * mp][n]);
        acc[2 * mp + 1][n] = MFMA16(a1k0, bq[n][0], acc[2 * mp + 1][n]);
        acc[2 * mp + 1][n] = MFMA16(a1k1, bq[n][1], acc[2 * mp + 1][n]);
      }
      __builtin_amdgcn_s_setprio(0);
      if (mp == 3) asm volatile("s_waitcnt vmcnt(0)" ::: "memory");
      __builtin_amdgcn_s_barrier();                       // close
      asm volatile("" ::: "memory");
    }
  }

  // ---- epilogue
  const int grow0 = bm + wr * 128 + (lane >> 4) * 4;
  const int gcol0 = bn + wc * 64 + l15;
#pragma unroll
  for (int i = 0; i < 8; i++)
#pragma unroll
    for (int j = 0; j < 4; j++) {
      int grow = grow0 + i * 16;
      int gcol = gcol0 + j * 16;
      if (EPI == 1) {
#pragma unroll
        for (int r = 0; r < 4; r++)
          Cf[(size_t)(grow + r) * 2048 + gcol] = acc[i][j][r];
      } else {
        int mat = gcol >> 11, mcol = gcol & 2047;
        if (mat == 2) {
          int b = grow >> 11;
          bf16x4 pk = {(bf16)acc[i][j][0], (bf16)acc[i][j][1],
                       (bf16)acc[i][j][2], (bf16)acc[i][j][3]};
          *(bf16x4*)&Cvt[((size_t)(b * 2048 + mcol)) * 2048 + (grow & 2047)] = pk;
        } else {
          bf16* Cp = (mat == 0) ? Cq : Ck;
#pragma unroll
          for (int r = 0; r < 4; r++)
            Cp[(size_t)(grow + r) * 2048 + mcol] = (bf16)acc[i][j][r];
        }
      }
    }
}

// ---------------- fused RMSNorm + RoPE, in place ----------------
__global__ __launch_bounds__(256) void normrope_kernel(bf16* __restrict__ T,
                                                       const float* __restrict__ w,
                                                       const float* __restrict__ cs,
                                                       const float* __restrict__ sn) {
  int row = blockIdx.x * 4 + (threadIdx.x >> 6);
  int lane = threadIdx.x & 63;
  int bl = row >> 4;
  int h = row & 15;
  bf16* p = T + (size_t)bl * EMB + h * HD;
  float v1 = (float)p[lane];
  float v2 = (float)p[lane + 64];
  float ss = v1 * v1 + v2 * v2;
#pragma unroll
  for (int m = 32; m; m >>= 1) ss += __shfl_xor(ss, m, 64);
  float r = rsqrtf(ss * (1.0f / 128.0f) + 1e-6f);
  float n1 = v1 * r * w[lane];
  float n2 = v2 * r * w[lane + 64];
  float c = cs[(size_t)bl * 64 + lane];
  float s = sn[(size_t)bl * 64 + lane];
  p[lane]      = (bf16)(n1 * c - n2 * s);
  p[lane + 64] = (bf16)(n1 * s + n2 * c);
}

// ---------------- causal flash attention, bounded-exp softmax --------------
__device__ __forceinline__ void stage_kv(bf16* Ksb, bf16* Vsb,
                                         const bf16* gK, const bf16* gV,
                                         int kt, int w, int lane) {
#pragma unroll
  for (int i = 0; i < 4; i++) {
    int ck = i * 256 + w * 64 + lane;
    int kr = ck >> 4, kc = ck & 15;
    gll16(&Ksb[ck * 8], gK + (size_t)(kt * 64 + kr) * EMB + ((kc ^ (kr & 7)) * 8));
    int dr = ck >> 3, vc = ck & 7;
    gll16(&Vsb[ck * 8], gV + (size_t)dr * L_SEQ + kt * 64 + ((vc ^ (dr & 7)) * 8));
  }
}

__global__ __launch_bounds__(256) void fattn_kernel(const bf16* __restrict__ Q,
                                                    const bf16* __restrict__ K,
                                                    const bf16* __restrict__ Vt,
                                                    bf16* __restrict__ AO) {
  __shared__ bf16 Ks[2][64 * 128];
  __shared__ bf16 Vs[2][64 * 128];
  __shared__ bf16 Ps[4 * 16 * 64];
  const int tid = threadIdx.x, lane = tid & 63, w = tid >> 6;

  int id = blockIdx.x + blockIdx.y * 32;
  int bh = id & 63;
  int qt = 31 - (id >> 6);
  const int b = bh >> 4, h = bh & 15;
  const size_t base = (size_t)b * L_SEQ * EMB + h * HD;
  const bf16* gK = K + base;
  const bf16* gV = Vt + (size_t)(b * NH + h) * HD * L_SEQ;
  const int qrow0 = qt * 64 + w * 16;

  const float a_ = 0.08838834764831845f * 1.4426950408889634f;
  const float b_ = 12.0f * 1.4426950408889634f;

  bf16x8 qf[4];
  {
    const bf16* qp = Q + base + (size_t)(qrow0 + (lane & 15)) * EMB + ((lane >> 4) * 8);
#pragma unroll
    for (int c = 0; c < 4; c++) qf[c] = *(const bf16x8*)(qp + c * 32);
  }
  const bf16 one1 = (bf16)1.0f;
  const bf16x8 ones = {one1, one1, one1, one1, one1, one1, one1, one1};

  f32x4 O[8] = {};
  f32x4 lsum = {0.f, 0.f, 0.f, 0.f};
  const int qg0 = qrow0 + (lane >> 4) * 4;
  bf16* myP = Ps + w * 1024;

  stage_kv(Ks[0], Vs[0], gK, gV, 0, w, lane);
  asm volatile("s_waitcnt vmcnt(0)" ::: "memory");
  __builtin_amdgcn_s_barrier();
  asm volatile("" ::: "memory");

  for (int kt = 0; kt <= qt; kt++) {
    const int cur = kt & 1;
    if (kt < qt) stage_kv(Ks[cur ^ 1], Vs[cur ^ 1], gK, gV, kt + 1, w, lane);

    f32x4 S[4] = {};
    __builtin_amdgcn_s_setprio(1);
#pragma unroll
    for (int s = 0; s < 4; s++) {
      int row = s * 16 + (lane & 15);
#pragma unroll
      for (int c = 0; c < 4; c++) {
        int swc = (c * 4 + (lane >> 4)) ^ (row & 7);
        bf16x8 kf = *(const bf16x8*)&Ks[cur][row * 128 + swc * 8];
        S[s] = MFMA16(qf[c], kf, S[s]);
      }
    }
    __builtin_amdgcn_s_setprio(0);

    const bool diag = (kt == qt);
    const int prow = (lane >> 4) * 4;
#pragma unroll
    for (int s = 0; s < 4; s++) {
      int kg = kt * 64 + s * 16 + (lane & 15);
#pragma unroll
      for (int r = 0; r < 4; r++) {
        float e = exp2f(S[s][r] * a_ - b_);
        if (diag && kg > qg0 + r) e = 0.f;
        int row = prow + r;
        myP[(row * 64 + s * 16 + (lane & 15)) ^ ((row & 7) << 3)] = (bf16)e;
      }
    }
    bf16x8 pf[2];
#pragma unroll
    for (int kk = 0; kk < 2; kk++) {
      int row = lane & 15;
      int swc = (kk * 4 + (lane >> 4)) ^ (row & 7);
      pf[kk] = *(const bf16x8*)&myP[row * 64 + swc * 8];
    }
    __builtin_amdgcn_s_setprio(1);
    lsum = MFMA16(pf[0], ones, lsum);
    lsum = MFMA16(pf[1], ones, lsum);
#pragma unroll
    for (int ni = 0; ni < 8; ni++) {
#pragma unroll
      for (int kk = 0; kk < 2; kk++) {
        int drow = ni * 16 + (lane & 15);
        int swc = (kk * 4 + (lane >> 4)) ^ (drow & 7);
        bf16x8 vf = *(const bf16x8*)&Vs[cur][drow * 64 + swc * 8];
        O[ni] = MFMA16(pf[kk], vf, O[ni]);
      }
    }
    __builtin_amdgcn_s_setprio(0);

    asm volatile("s_waitcnt vmcnt(0)" ::: "memory");
    __builtin_amdgcn_s_barrier();
    asm volatile("" ::: "memory");
  }

#pragma unroll
  for (int ni = 0; ni < 8; ni++) {
#pragma unroll
    for (int r = 0; r < 4; r++) {
      float o = O[ni][r] / lsum[r];
      AO[(size_t)(b * L_SEQ + qg0 + r) * EMB + h * HD + ni * 16 + (lane & 15)] = (bf16)o;
    }
  }
}

extern "C" void kernel_launch(void* const* d_in, const int* in_sizes, int n_in,
                              void* d_out, int out_size, void* d_ws, size_t ws_size,
                              hipStream_t stream) {
  const float* x = (const float*)d_in[0];
  const float* cosp = (const float*)d_in[2];
  const float* sinp = (const float*)d_in[3];
  const float* Wq = (const float*)d_in[4];
  const float* Wk = (const float*)d_in[5];
  const float* Wv = (const float*)d_in[6];
  const float* Wo = (const float*)d_in[7];
  const float* qw = (const float*)d_in[8];
  const float* kw = (const float*)d_in[9];

  const size_t ACT = (size_t)BLROWS * EMB * sizeof(bf16);
  const size_t WGT = (size_t)EMB * EMB * sizeof(bf16);
  char* ws = (char*)d_ws;
  bf16* xb    = (bf16*)ws;          ws += ACT;
  bf16* WQKVb = (bf16*)ws;          ws += 3 * WGT;
  bf16* Wob   = (bf16*)ws;          ws += WGT;
  bf16* Qb    = (bf16*)ws;          ws += ACT;
  bf16* Kb    = (bf16*)ws;          ws += ACT;
  bf16* Vtb   = (bf16*)ws;          ws += ACT;
  bf16* AOb   = (bf16*)ws;          ws += ACT;

  f2b_kernel<<<2048, 256, 0, stream>>>(x, xb, BLROWS * EMB / 4);
  f2b_kernel<<<1024, 256, 0, stream>>>(Wq, WQKVb, EMB * EMB / 4);
  f2b_kernel<<<1024, 256, 0, stream>>>(Wk, WQKVb + (size_t)EMB * EMB, EMB * EMB / 4);
  f2b_kernel<<<1024, 256, 0, stream>>>(Wv, WQKVb + 2 * (size_t)EMB * EMB, EMB * EMB / 4);
  f2b_kernel<<<1024, 256, 0, stream>>>(Wo, Wob, EMB * EMB / 4);

  gemm256<0><<<768, 512, 0, stream>>>(xb, WQKVb, Qb, Kb, Vtb, nullptr, EMB);

  normrope_kernel<<<BLROWS * NH / 4, 256, 0, stream>>>(Qb, qw, cosp, sinp);
  normrope_kernel<<<BLROWS * NH / 4, 256, 0, stream>>>(Kb, kw, cosp, sinp);

  fattn_kernel<<<dim3(32, B_SZ * NH), 256, 0, stream>>>(Qb, Kb, Vtb, AOb);

  gemm256<1><<<256, 512, 0, stream>>>(AOb, Wob, nullptr, nullptr, nullptr,
                                      (float*)d_out, EMB);
}